// Round 1
// baseline (101.387 us; speedup 1.0000x reference)
//
#include <hip/hip_runtime.h>

#define B_   128
#define N_   128
#define FA   64
#define FB   16
#define K1   144   // 2*FA + FB
#define HID  512
#define OUT_ 128

// ---------------------------------------------------------------------------
// Kernel A: per (b, j-half) compute deg + agg_bond over i, then write
// h_in[b, j, 0:144] = [atom | atom*deg | agg_bond].
// grid = 256 blocks (b*2 + jhalf), 512 threads.
// ---------------------------------------------------------------------------
__global__ __launch_bounds__(512) void k_build_hin(
    const float* __restrict__ atom, const float* __restrict__ bond,
    const float* __restrict__ adj, float* __restrict__ hin) {
  const int b  = blockIdx.x >> 1;
  const int j0 = (blockIdx.x & 1) * 64;
  const int t  = threadIdx.x;

  const float* adjb  = adj  + (size_t)b * N_ * N_;
  const float* bondb = bond + (size_t)b * N_ * N_ * FB + (size_t)j0 * FB;

  // thread t owns (j = j0 + t>>3, f-pair = (t&7)*2)
  const int jl = t >> 3;        // 0..63
  const int fp = (t & 7) * 2;   // 0,2,..,14
  float2 acc = make_float2(0.f, 0.f);

  for (int i = 0; i < N_; ++i) {
    const float  a  = adjb[i * N_ + j0 + jl];
    const float2 bv = *reinterpret_cast<const float2*>(
        &bondb[(size_t)i * N_ * FB + jl * FB + fp]);
    acc.x += a * bv.x;
    acc.y += a * bv.y;
  }

  __shared__ float s_agg[64][16];
  __shared__ float s_deg[64];
  s_agg[jl][fp]     = acc.x;
  s_agg[jl][fp + 1] = acc.y;
  if (t < 64) {
    float d = 0.f;
    for (int i = 0; i < N_; ++i) d += adjb[i * N_ + j0 + t];
    s_deg[t] = d;
  }
  __syncthreads();

  const float* atomb = atom + (size_t)b * N_ * FA + (size_t)j0 * FA;
  float*       hb    = hin  + (size_t)b * N_ * K1 + (size_t)j0 * K1;
  for (int idx = t; idx < 64 * K1; idx += 512) {
    const int j = idx / K1;
    const int k = idx - j * K1;
    float v;
    if (k < FA)           v = atomb[j * FA + k];
    else if (k < 2 * FA)  v = atomb[j * FA + (k - FA)] * s_deg[j];
    else                  v = s_agg[j][k - 2 * FA];
    hb[idx] = v;
  }
}

// ---------------------------------------------------------------------------
// Kernel B: per (b, 64-col tile of HID): h = relu(h_in @ W1 + b1), then
// column-sum over the 128 j rows -> s[b, n]. grid = (8, 128), 256 threads.
// ---------------------------------------------------------------------------
__global__ __launch_bounds__(256) void k_gemm1(
    const float* __restrict__ hin, const float* __restrict__ W1,
    const float* __restrict__ b1, float* __restrict__ s_out) {
  const int b  = blockIdx.y;
  const int nt = blockIdx.x;            // 0..7
  const int t  = threadIdx.x;
  const int tx = t & 15, ty = t >> 4;

  __shared__ float sW1[K1][64];
  __shared__ float sA[32][K1 + 1];      // +1 pad: breaks 4-way bank aliasing
  __shared__ float sRed[16][64];

  const float* W1t = W1 + nt * 64;
  for (int idx = t; idx < K1 * 64; idx += 256) {
    const int k = idx >> 6, n = idx & 63;
    sW1[k][n] = W1t[k * HID + n];
  }

  float bias[4];
#pragma unroll
  for (int c = 0; c < 4; ++c) bias[c] = b1[nt * 64 + tx * 4 + c];

  float partial[4] = {0.f, 0.f, 0.f, 0.f};
  const float* hb = hin + (size_t)b * N_ * K1;

  for (int jc = 0; jc < 4; ++jc) {
    __syncthreads();
    for (int idx = t; idx < 32 * K1; idx += 256) {
      const int jj = idx / K1;
      const int k  = idx - jj * K1;
      sA[jj][k] = hb[jc * 32 * K1 + idx];
    }
    __syncthreads();

    float acc0[4] = {0.f, 0.f, 0.f, 0.f};
    float acc1[4] = {0.f, 0.f, 0.f, 0.f};
    const int j0 = ty * 2;
#pragma unroll 4
    for (int k = 0; k < K1; ++k) {
      const float  a0 = sA[j0][k];
      const float  a1 = sA[j0 + 1][k];
      const float4 w  = *reinterpret_cast<const float4*>(&sW1[k][tx * 4]);
      acc0[0] += a0 * w.x; acc0[1] += a0 * w.y;
      acc0[2] += a0 * w.z; acc0[3] += a0 * w.w;
      acc1[0] += a1 * w.x; acc1[1] += a1 * w.y;
      acc1[2] += a1 * w.z; acc1[3] += a1 * w.w;
    }
#pragma unroll
    for (int c = 0; c < 4; ++c)
      partial[c] += fmaxf(acc0[c] + bias[c], 0.f) +
                    fmaxf(acc1[c] + bias[c], 0.f);
  }

  __syncthreads();
#pragma unroll
  for (int c = 0; c < 4; ++c) sRed[ty][tx * 4 + c] = partial[c];
  __syncthreads();
  for (int srd = 8; srd > 0; srd >>= 1) {
    if (ty < srd) {
#pragma unroll
      for (int c = 0; c < 4; ++c)
        sRed[ty][tx * 4 + c] += sRed[ty + srd][tx * 4 + c];
    }
    __syncthreads();
  }
  if (ty == 0) {
#pragma unroll
    for (int c = 0; c < 4; ++c)
      s_out[b * HID + nt * 64 + tx * 4 + c] = sRed[0][tx * 4 + c];
  }
}

// ---------------------------------------------------------------------------
// Kernel C: out[b, o] = s[b, :] @ W2[:, o] + N * b2[o].  grid = 128, 128 thr.
// ---------------------------------------------------------------------------
__global__ __launch_bounds__(128) void k_out(
    const float* __restrict__ s, const float* __restrict__ W2,
    const float* __restrict__ b2, float* __restrict__ out) {
  const int b = blockIdx.x;
  const int o = threadIdx.x;
  __shared__ float ss[HID];
  for (int k = o; k < HID; k += 128) ss[k] = s[b * HID + k];
  __syncthreads();
  float acc = 0.f;
  for (int k = 0; k < HID; ++k) acc += ss[k] * W2[k * OUT_ + o];
  out[b * OUT_ + o] = acc + (float)N_ * b2[o];
}

// ---------------------------------------------------------------------------
extern "C" void kernel_launch(void* const* d_in, const int* in_sizes, int n_in,
                              void* d_out, int out_size, void* d_ws, size_t ws_size,
                              hipStream_t stream) {
  const float* atom = (const float*)d_in[0];
  const float* bond = (const float*)d_in[1];
  const float* adj  = (const float*)d_in[2];
  const float* W1   = (const float*)d_in[3];
  const float* b1   = (const float*)d_in[4];
  const float* W2   = (const float*)d_in[5];
  const float* b2   = (const float*)d_in[6];
  float* out = (float*)d_out;

  float* hin = (float*)d_ws;                       // 16384 x 144 fp32 (9.44 MB)
  float* s   = hin + (size_t)B_ * N_ * K1;         // 128 x 512 fp32 (0.26 MB)

  k_build_hin<<<B_ * 2, 512, 0, stream>>>(atom, bond, adj, hin);
  k_gemm1<<<dim3(8, B_), 256, 0, stream>>>(hin, W1, b1, s);
  k_out<<<B_, 128, 0, stream>>>(s, W2, b2, out);
}

// Round 2
// 61.753 us; speedup vs baseline: 1.6418x; 1.6418x over previous
//
#include <hip/hip_runtime.h>
#include <hip/hip_bf16.h>

#define B_   128
#define N_   128
#define FA   64
#define FB   16
#define K1   144   // 2*FA + FB
#define KP   160   // K padded to 5 * 32
#define HID  512
#define OUT_ 128

typedef __attribute__((ext_vector_type(8))) short short8;
typedef __attribute__((ext_vector_type(4))) float f32x4;

__device__ __forceinline__ ushort f2b(float v) {
  __hip_bfloat16 h = __float2bfloat16(v);
  return *reinterpret_cast<ushort*>(&h);
}

// ---------------------------------------------------------------------------
// Prep: W1 [144][512] fp32 -> bf16 fragment-ordered W1f.
// Unit U = (ntg*5 + ks)*64 + g*16 + c holds 8 bf16: W1[ks*32+g*8+e][ntg*16+c],
// zero-padded for k >= 144.  10240 units. grid 40 x 256.
// ---------------------------------------------------------------------------
__global__ __launch_bounds__(256) void k_prepw(const float* __restrict__ W1,
                                               ushort* __restrict__ w1f) {
  const int U  = blockIdx.x * 256 + threadIdx.x;
  const int c  = U & 15;
  const int g  = (U >> 4) & 3;
  const int t5 = U >> 6;
  const int ks = t5 % 5;
  const int ntg = t5 / 5;
  const int n  = ntg * 16 + c;
  const int k0 = ks * 32 + g * 8;
  short8 v;
#pragma unroll
  for (int e = 0; e < 8; ++e) {
    const int k = k0 + e;
    const float x = (k < K1) ? W1[k * HID + n] : 0.f;
    v[e] = (short)f2b(x);
  }
  reinterpret_cast<short8*>(w1f)[U] = v;
}

// ---------------------------------------------------------------------------
// Aggregation: block = (b, m) with m the 16-row j-tile. Sparse predicated
// bond gather, then write h_in tile in bf16 FRAGMENT ORDER:
//   unit (ks,g,r) at hinf[(b*8+m)*320 + ks*64 + g*16 + r] = row r, k=ks*32+g*8..+7
// grid 1024 x 256.
// ---------------------------------------------------------------------------
__global__ __launch_bounds__(256) void k_agg(
    const float* __restrict__ atom, const float* __restrict__ bond,
    const float* __restrict__ adj, ushort* __restrict__ hinf) {
  const int b  = blockIdx.x >> 3;
  const int m  = blockIdx.x & 7;
  const int j0 = m * 16;
  const int t  = threadIdx.x;
  const int jl = t >> 4;   // 0..15 local row
  const int f  = t & 15;   // bond feature

  __shared__ float sAdj[N_][16];   // 8 KB
  const float* adjb = adj + (size_t)b * N_ * N_ + j0;
  for (int r = t; r < N_ * 16; r += 256) {
    const int i = r >> 4, jj = r & 15;
    sAdj[i][jj] = adjb[(size_t)i * N_ + jj];
  }
  __syncthreads();

  float acc = 0.f, deg = 0.f;
  const float* bp = bond + ((size_t)b * N_ * N_ + (size_t)(j0 + jl)) * FB + f;
#pragma unroll 4
  for (int i = 0; i < N_; ++i) {
    const float a = sAdj[i][jl];
    deg += a;
    if (a != 0.f) acc += bp[(size_t)i * N_ * FB];  // adj is exactly 0/1
  }

  __shared__ ushort sRow[16][KP];  // 5 KB
  const float* ab = atom + ((size_t)b * N_ + j0 + jl) * FA;
  for (int c = f; c < FA; c += 16) {
    const float av = ab[c];
    sRow[jl][c]      = f2b(av);
    sRow[jl][FA + c] = f2b(av * deg);
  }
  sRow[jl][2 * FA + f] = f2b(acc);
  sRow[jl][K1 + f]     = 0;
  __syncthreads();

  uint4* dst = reinterpret_cast<uint4*>(hinf) + (size_t)(b * 8 + m) * 320;
  for (int u = t; u < 320; u += 256) {
    const int s = u >> 4, j2 = u & 15;        // s = ks*4 + g
    const int ks = s >> 2, g = s & 3;
    dst[ks * 64 + g * 16 + j2] =
        *reinterpret_cast<const uint4*>(&sRow[j2][s * 8]);
  }
}

// ---------------------------------------------------------------------------
// GEMM1 + bias + relu + column-sum.  block = (b, n-half 256). 512 thr = 8
// waves; wave w owns 32 cols. MFMA 16x16x32 bf16; A staged linear in LDS.
// grid 256 x 512.
// ---------------------------------------------------------------------------
__global__ __launch_bounds__(512) void k_gemm(
    const ushort* __restrict__ hinf, const ushort* __restrict__ w1f,
    const float* __restrict__ b1, float* __restrict__ s_out) {
  const int b  = blockIdx.x >> 1;
  const int nh = blockIdx.x & 1;
  const int t  = threadIdx.x;
  const int w  = t >> 6;
  const int l  = t & 63;

  __shared__ ushort sA[40 * 512];  // 40960 B, fragment-ordered h_in[b]

  const uint4* g4 = reinterpret_cast<const uint4*>(hinf) + (size_t)b * 2560;
  uint4* s4 = reinterpret_cast<uint4*>(sA);
  for (int u = t; u < 2560; u += 512) s4[u] = g4[u];

  const int n0 = nh * 256 + w * 32;
  const short8* w8 = reinterpret_cast<const short8*>(w1f);
  short8 bfrag[2][5];
#pragma unroll
  for (int nt = 0; nt < 2; ++nt) {
    const int ntg = (n0 >> 4) + nt;
#pragma unroll
    for (int ks = 0; ks < 5; ++ks)
      bfrag[nt][ks] = w8[(ntg * 5 + ks) * 64 + l];
  }
  float bias[2];
#pragma unroll
  for (int nt = 0; nt < 2; ++nt) bias[nt] = b1[n0 + nt * 16 + (l & 15)];

  __syncthreads();

  const short8* a8 = reinterpret_cast<const short8*>(sA);
  float cs[2] = {0.f, 0.f};
  for (int m = 0; m < 8; ++m) {
    short8 af[5];
#pragma unroll
    for (int ks = 0; ks < 5; ++ks) af[ks] = a8[(m * 5 + ks) * 64 + l];
#pragma unroll
    for (int nt = 0; nt < 2; ++nt) {
      f32x4 acc = {0.f, 0.f, 0.f, 0.f};
#pragma unroll
      for (int ks = 0; ks < 5; ++ks)
        acc = __builtin_amdgcn_mfma_f32_16x16x32_bf16(af[ks], bfrag[nt][ks],
                                                      acc, 0, 0, 0);
      float p = 0.f;
#pragma unroll
      for (int r = 0; r < 4; ++r) p += fmaxf(acc[r] + bias[nt], 0.f);
      cs[nt] += p;
    }
  }

#pragma unroll
  for (int nt = 0; nt < 2; ++nt) {
    float v = cs[nt];
    v += __shfl_xor(v, 16);
    v += __shfl_xor(v, 32);
    if ((l >> 4) == 0) s_out[b * HID + n0 + nt * 16 + (l & 15)] = v;
  }
}

// ---------------------------------------------------------------------------
// out[b,o] = s[b,:] @ W2[:,o] + N * b2[o]
// ---------------------------------------------------------------------------
__global__ __launch_bounds__(128) void k_out(
    const float* __restrict__ s, const float* __restrict__ W2,
    const float* __restrict__ b2, float* __restrict__ out) {
  const int b = blockIdx.x;
  const int o = threadIdx.x;
  __shared__ float ss[HID];
  for (int k = o; k < HID; k += 128) ss[k] = s[b * HID + k];
  __syncthreads();
  float acc = 0.f;
  for (int k = 0; k < HID; ++k) acc += ss[k] * W2[k * OUT_ + o];
  out[b * OUT_ + o] = acc + (float)N_ * b2[o];
}

// ---------------------------------------------------------------------------
extern "C" void kernel_launch(void* const* d_in, const int* in_sizes, int n_in,
                              void* d_out, int out_size, void* d_ws, size_t ws_size,
                              hipStream_t stream) {
  const float* atom = (const float*)d_in[0];
  const float* bond = (const float*)d_in[1];
  const float* adj  = (const float*)d_in[2];
  const float* W1   = (const float*)d_in[3];
  const float* b1   = (const float*)d_in[4];
  const float* W2   = (const float*)d_in[5];
  const float* b2   = (const float*)d_in[6];
  float* out = (float*)d_out;

  ushort* hinf = (ushort*)d_ws;                       // 128*2560 units *16B = 5.24 MB
  ushort* w1f  = hinf + (size_t)B_ * 2560 * 8;        // 10240 units = 160 KB
  float*  s    = (float*)(w1f + 10240 * 8);           // 128x512 fp32

  k_prepw<<<40, 256, 0, stream>>>(W1, w1f);
  k_agg<<<B_ * 8, 256, 0, stream>>>(atom, bond, adj, hinf);
  k_gemm<<<B_ * 2, 512, 0, stream>>>(hinf, w1f, b1, s);
  k_out<<<B_, 128, 0, stream>>>(s, W2, b2, out);
}

// Round 3
// 31.818 us; speedup vs baseline: 3.1865x; 1.9408x over previous
//
#include <hip/hip_runtime.h>
#include <hip/hip_bf16.h>

#define B_   128
#define N_   128
#define FA   64
#define FB   16
#define K1   144   // 2*FA + FB
#define KP   160   // K padded to 5 * 32
#define HID  512
#define OUT_ 128

typedef __attribute__((ext_vector_type(8))) short short8;
typedef __attribute__((ext_vector_type(4))) float f32x4;

__device__ __forceinline__ ushort f2b(float v) {
  __hip_bfloat16 h = __float2bfloat16(v);
  return *reinterpret_cast<ushort*>(&h);
}

// ---------------------------------------------------------------------------
// Kernel A (merged): blocks 0..39 convert W1 -> bf16 fragment order;
// blocks 40.. do sparse aggregation + h_in fragment-order build.
//
// W1f unit U = (ntg*5 + ks)*64 + g*16 + c holds 8 bf16:
//   W1[ks*32+g*8+e][ntg*16+c], zero-padded k>=144.
// hinf unit at (b*8+m)*320 + ks*64 + g*16 + r = row r of tile m,
//   k = ks*32+g*8 .. +7.
// ---------------------------------------------------------------------------
__global__ __launch_bounds__(256) void k_prep_agg(
    const float* __restrict__ atom, const float* __restrict__ bond,
    const float* __restrict__ adj, const float* __restrict__ W1,
    ushort* __restrict__ w1f, ushort* __restrict__ hinf) {
  const int t = threadIdx.x;

  if (blockIdx.x < 40) {                       // ---- W1 conversion role ----
    const int U  = blockIdx.x * 256 + t;
    const int c  = U & 15;
    const int g  = (U >> 4) & 3;
    const int t5 = U >> 6;
    const int ks = t5 % 5;
    const int ntg = t5 / 5;
    const int n  = ntg * 16 + c;
    const int k0 = ks * 32 + g * 8;
    short8 v;
#pragma unroll
    for (int e = 0; e < 8; ++e) {
      const int k = k0 + e;
      v[e] = (short)f2b((k < K1) ? W1[k * HID + n] : 0.f);
    }
    reinterpret_cast<short8*>(w1f)[U] = v;
    return;
  }

  // ---- aggregation role ----
  const int bid = blockIdx.x - 40;
  const int b  = bid >> 3;
  const int m  = bid & 7;
  const int j0 = m * 16;
  const int jl = t >> 4;   // 0..15 local row
  const int f  = t & 15;   // bond feature

  __shared__ float  sAdj[N_][16];   // 8 KB
  __shared__ ushort sList[16][N_];  // 4 KB compact active-i lists
  __shared__ int    sCnt[16];
  __shared__ ushort sRow[16][KP];   // 5 KB

  // stage adj column-slab [128 i][16 j], float4-vectorized
  const float* adjb = adj + (size_t)b * N_ * N_ + j0;
  for (int u = t; u < N_ * 4; u += 256) {
    const int i = u >> 2, q = u & 3;
    *reinterpret_cast<float4*>(&sAdj[i][q * 4]) =
        *reinterpret_cast<const float4*>(&adjb[(size_t)i * N_ + q * 4]);
  }
  __syncthreads();

  // ballot-compact: wave w handles j = w*4 .. w*4+3
  const int wv = t >> 6, l = t & 63;
#pragma unroll
  for (int q = 0; q < 4; ++q) {
    const int jj = wv * 4 + q;
    const float a0 = sAdj[l][jj];
    const float a1 = sAdj[l + 64][jj];
    const unsigned long long m0 = __ballot(a0 != 0.f);
    const unsigned long long m1 = __ballot(a1 != 0.f);
    const int c0 = __popcll(m0);
    unsigned int p0 = __builtin_amdgcn_mbcnt_lo((unsigned)m0, 0u);
    p0 = __builtin_amdgcn_mbcnt_hi((unsigned)(m0 >> 32), p0);
    if (a0 != 0.f) sList[jj][p0] = (ushort)l;
    unsigned int p1 = __builtin_amdgcn_mbcnt_lo((unsigned)m1, 0u);
    p1 = __builtin_amdgcn_mbcnt_hi((unsigned)(m1 >> 32), p1);
    if (a1 != 0.f) sList[jj][c0 + p1] = (ushort)(l + 64);
    if (l == 0) sCnt[jj] = c0 + __popcll(m1);
  }
  __syncthreads();

  // branch-free pipelined gather over compact list (adj is 0/1 -> deg = cnt)
  const int cnt = sCnt[jl];
  const float* bpp = bond + ((size_t)b * N_ * N_ + (j0 + jl)) * FB + f;
  float a0 = 0.f, a1 = 0.f, a2 = 0.f, a3 = 0.f;
  int e = 0;
  for (; e + 4 <= cnt; e += 4) {
    const int i0 = sList[jl][e], i1 = sList[jl][e + 1];
    const int i2 = sList[jl][e + 2], i3 = sList[jl][e + 3];
    a0 += bpp[(size_t)i0 * N_ * FB];
    a1 += bpp[(size_t)i1 * N_ * FB];
    a2 += bpp[(size_t)i2 * N_ * FB];
    a3 += bpp[(size_t)i3 * N_ * FB];
  }
  for (; e < cnt; ++e) a0 += bpp[(size_t)sList[jl][e] * N_ * FB];
  const float aggv = (a0 + a1) + (a2 + a3);
  const float deg  = (float)cnt;

  // build bf16 row [atom | atom*deg | agg | 0-pad]
  const float* ab = atom + ((size_t)b * N_ + j0 + jl) * FA;
  for (int c = f; c < FA; c += 16) {
    const float av = ab[c];
    sRow[jl][c]      = f2b(av);
    sRow[jl][FA + c] = f2b(av * deg);
  }
  sRow[jl][2 * FA + f] = f2b(aggv);
  sRow[jl][K1 + f]     = 0;
  __syncthreads();

  uint4* dst = reinterpret_cast<uint4*>(hinf) + (size_t)(b * 8 + m) * 320;
  for (int u = t; u < 320; u += 256) {
    const int s = u >> 4, j2 = u & 15;        // s = ks*4 + g
    const int ks = s >> 2, g = s & 3;
    dst[ks * 64 + g * 16 + j2] =
        *reinterpret_cast<const uint4*>(&sRow[j2][s * 8]);
  }
}

// ---------------------------------------------------------------------------
// GEMM1 + bias + relu + column-sum.  block = (b, n-half 256). 512 thr = 8
// waves; wave w owns 32 cols. MFMA 16x16x32 bf16; A fragment-order in LDS.
// ---------------------------------------------------------------------------
__global__ __launch_bounds__(512) void k_gemm(
    const ushort* __restrict__ hinf, const ushort* __restrict__ w1f,
    const float* __restrict__ b1, float* __restrict__ s_out) {
  const int b  = blockIdx.x >> 1;
  const int nh = blockIdx.x & 1;
  const int t  = threadIdx.x;
  const int w  = t >> 6;
  const int l  = t & 63;

  __shared__ ushort sA[40 * 512];  // 40960 B

  const uint4* g4 = reinterpret_cast<const uint4*>(hinf) + (size_t)b * 2560;
  uint4* s4 = reinterpret_cast<uint4*>(sA);
  for (int u = t; u < 2560; u += 512) s4[u] = g4[u];

  const int n0 = nh * 256 + w * 32;
  const short8* w8 = reinterpret_cast<const short8*>(w1f);
  short8 bfrag[2][5];
#pragma unroll
  for (int nt = 0; nt < 2; ++nt) {
    const int ntg = (n0 >> 4) + nt;
#pragma unroll
    for (int ks = 0; ks < 5; ++ks)
      bfrag[nt][ks] = w8[(ntg * 5 + ks) * 64 + l];
  }
  float bias[2];
#pragma unroll
  for (int nt = 0; nt < 2; ++nt) bias[nt] = b1[n0 + nt * 16 + (l & 15)];

  __syncthreads();

  const short8* a8 = reinterpret_cast<const short8*>(sA);
  float cs[2] = {0.f, 0.f};
  for (int m = 0; m < 8; ++m) {
    short8 af[5];
#pragma unroll
    for (int ks = 0; ks < 5; ++ks) af[ks] = a8[(m * 5 + ks) * 64 + l];
#pragma unroll
    for (int nt = 0; nt < 2; ++nt) {
      f32x4 acc = {0.f, 0.f, 0.f, 0.f};
#pragma unroll
      for (int ks = 0; ks < 5; ++ks)
        acc = __builtin_amdgcn_mfma_f32_16x16x32_bf16(af[ks], bfrag[nt][ks],
                                                      acc, 0, 0, 0);
      float p = 0.f;
#pragma unroll
      for (int r = 0; r < 4; ++r) p += fmaxf(acc[r] + bias[nt], 0.f);
      cs[nt] += p;
    }
  }

#pragma unroll
  for (int nt = 0; nt < 2; ++nt) {
    float v = cs[nt];
    v += __shfl_xor(v, 16);
    v += __shfl_xor(v, 32);
    if ((l >> 4) == 0) s_out[b * HID + n0 + nt * 16 + (l & 15)] = v;
  }
}

// ---------------------------------------------------------------------------
// out[b,o] = s[b,:] @ W2[:,o] + N * b2[o].  2-way k-split, 256 thr.
// ---------------------------------------------------------------------------
__global__ __launch_bounds__(256) void k_out(
    const float* __restrict__ s, const float* __restrict__ W2,
    const float* __restrict__ b2, float* __restrict__ out) {
  const int b = blockIdx.x;
  const int t = threadIdx.x;
  const int o = t & 127, kh = t >> 7;
  __shared__ float ss[HID];
  __shared__ float red[2][128];
  for (int k = t; k < HID; k += 256) ss[k] = s[b * HID + k];
  __syncthreads();
  float acc = 0.f;
  const int k0 = kh * 256;
  for (int k = k0; k < k0 + 256; ++k) acc += ss[k] * W2[k * OUT_ + o];
  red[kh][o] = acc;
  __syncthreads();
  if (kh == 0) out[b * OUT_ + o] = red[0][o] + red[1][o] + (float)N_ * b2[o];
}

// ---------------------------------------------------------------------------
extern "C" void kernel_launch(void* const* d_in, const int* in_sizes, int n_in,
                              void* d_out, int out_size, void* d_ws, size_t ws_size,
                              hipStream_t stream) {
  const float* atom = (const float*)d_in[0];
  const float* bond = (const float*)d_in[1];
  const float* adj  = (const float*)d_in[2];
  const float* W1   = (const float*)d_in[3];
  const float* b1   = (const float*)d_in[4];
  const float* W2   = (const float*)d_in[5];
  const float* b2   = (const float*)d_in[6];
  float* out = (float*)d_out;

  ushort* hinf = (ushort*)d_ws;                       // 128*2560*16B = 5.24 MB
  ushort* w1f  = hinf + (size_t)B_ * 2560 * 8;        // 160 KB
  float*  s    = (float*)(w1f + 10240 * 8);           // 128x512 fp32

  k_prep_agg<<<40 + B_ * 8, 256, 0, stream>>>(atom, bond, adj, W1, w1f, hinf);
  k_gemm<<<B_ * 2, 512, 0, stream>>>(hinf, w1f, b1, s);
  k_out<<<B_, 128 * 2, 0, stream>>>(s, W2, b2, out);
}

// Round 4
// 31.124 us; speedup vs baseline: 3.2576x; 1.0223x over previous
//
#include <hip/hip_runtime.h>
#include <hip/hip_bf16.h>

#define B_   128
#define N_   128
#define FA   64
#define FB   16
#define K1   144   // 2*FA + FB
#define KP   160   // K padded to 5 * 32
#define HID  512
#define OUT_ 128

typedef __attribute__((ext_vector_type(8))) short short8;
typedef __attribute__((ext_vector_type(4))) float f32x4;

__device__ __forceinline__ ushort f2b(float v) {
  __hip_bfloat16 h = __float2bfloat16(v);
  return *reinterpret_cast<ushort*>(&h);
}

// ---------------------------------------------------------------------------
// Kernel A (merged): blocks 0..39 convert W1 -> bf16 fragment order;
// blocks 40.. do sparse aggregation + h_in fragment-order build.
// ---------------------------------------------------------------------------
__global__ __launch_bounds__(256) void k_prep_agg(
    const float* __restrict__ atom, const float* __restrict__ bond,
    const float* __restrict__ adj, const float* __restrict__ W1,
    ushort* __restrict__ w1f, ushort* __restrict__ hinf) {
  const int t = threadIdx.x;

  if (blockIdx.x < 40) {                       // ---- W1 conversion role ----
    const int U  = blockIdx.x * 256 + t;
    const int c  = U & 15;
    const int g  = (U >> 4) & 3;
    const int t5 = U >> 6;
    const int ks = t5 % 5;
    const int ntg = t5 / 5;
    const int n  = ntg * 16 + c;
    const int k0 = ks * 32 + g * 8;
    short8 v;
#pragma unroll
    for (int e = 0; e < 8; ++e) {
      const int k = k0 + e;
      v[e] = (short)f2b((k < K1) ? W1[k * HID + n] : 0.f);
    }
    reinterpret_cast<short8*>(w1f)[U] = v;
    return;
  }

  // ---- aggregation role ----
  const int bid = blockIdx.x - 40;
  const int b  = bid >> 3;
  const int m  = bid & 7;
  const int j0 = m * 16;
  const int jl = t >> 4;   // 0..15 local row
  const int f  = t & 15;   // bond feature

  __shared__ float  sAdj[N_][16];   // 8 KB
  __shared__ ushort sList[16][N_];  // 4 KB compact active-i lists
  __shared__ int    sCnt[16];
  __shared__ ushort sRow[16][KP];   // 5 KB

  // stage adj column-slab [128 i][16 j], float4-vectorized
  const float* adjb = adj + (size_t)b * N_ * N_ + j0;
  for (int u = t; u < N_ * 4; u += 256) {
    const int i = u >> 2, q = u & 3;
    *reinterpret_cast<float4*>(&sAdj[i][q * 4]) =
        *reinterpret_cast<const float4*>(&adjb[(size_t)i * N_ + q * 4]);
  }
  __syncthreads();

  // ballot-compact: wave w handles j = w*4 .. w*4+3
  const int wv = t >> 6, l = t & 63;
#pragma unroll
  for (int q = 0; q < 4; ++q) {
    const int jj = wv * 4 + q;
    const float a0 = sAdj[l][jj];
    const float a1 = sAdj[l + 64][jj];
    const unsigned long long m0 = __ballot(a0 != 0.f);
    const unsigned long long m1 = __ballot(a1 != 0.f);
    const int c0 = __popcll(m0);
    unsigned int p0 = __builtin_amdgcn_mbcnt_lo((unsigned)m0, 0u);
    p0 = __builtin_amdgcn_mbcnt_hi((unsigned)(m0 >> 32), p0);
    if (a0 != 0.f) sList[jj][p0] = (ushort)l;
    unsigned int p1 = __builtin_amdgcn_mbcnt_lo((unsigned)m1, 0u);
    p1 = __builtin_amdgcn_mbcnt_hi((unsigned)(m1 >> 32), p1);
    if (a1 != 0.f) sList[jj][c0 + p1] = (ushort)(l + 64);
    if (l == 0) sCnt[jj] = c0 + __popcll(m1);
  }
  __syncthreads();

  // branch-free pipelined gather over compact list (adj is 0/1 -> deg = cnt)
  const int cnt = sCnt[jl];
  const float* bpp = bond + ((size_t)b * N_ * N_ + (j0 + jl)) * FB + f;
  float a0 = 0.f, a1 = 0.f, a2 = 0.f, a3 = 0.f;
  int e = 0;
  for (; e + 4 <= cnt; e += 4) {
    const int i0 = sList[jl][e], i1 = sList[jl][e + 1];
    const int i2 = sList[jl][e + 2], i3 = sList[jl][e + 3];
    a0 += bpp[(size_t)i0 * N_ * FB];
    a1 += bpp[(size_t)i1 * N_ * FB];
    a2 += bpp[(size_t)i2 * N_ * FB];
    a3 += bpp[(size_t)i3 * N_ * FB];
  }
  for (; e < cnt; ++e) a0 += bpp[(size_t)sList[jl][e] * N_ * FB];
  const float aggv = (a0 + a1) + (a2 + a3);
  const float deg  = (float)cnt;

  // build bf16 row [atom | atom*deg | agg | 0-pad]
  const float* ab = atom + ((size_t)b * N_ + j0 + jl) * FA;
  for (int c = f; c < FA; c += 16) {
    const float av = ab[c];
    sRow[jl][c]      = f2b(av);
    sRow[jl][FA + c] = f2b(av * deg);
  }
  sRow[jl][2 * FA + f] = f2b(aggv);
  sRow[jl][K1 + f]     = 0;
  __syncthreads();

  uint4* dst = reinterpret_cast<uint4*>(hinf) + (size_t)(b * 8 + m) * 320;
  for (int u = t; u < 320; u += 256) {
    const int s = u >> 4, j2 = u & 15;        // s = ks*4 + g
    const int ks = s >> 2, g = s & 3;
    dst[ks * 64 + g * 16 + j2] =
        *reinterpret_cast<const uint4*>(&sRow[j2][s * 8]);
  }
}

// ---------------------------------------------------------------------------
// Fused GEMM1 + bias + relu + column-sum + (s @ W2) epilogue.
// block = (b, n-half). 512 thr = 8 waves; wave w owns 32 cols of the half.
// Each block atomically adds its half's contribution to out[b,:].
// out must be zeroed before launch (exactly 2 fp32 adds per element, fp add
// is commutative -> bitwise deterministic).
// ---------------------------------------------------------------------------
__global__ __launch_bounds__(512) void k_gemm_out(
    const ushort* __restrict__ hinf, const ushort* __restrict__ w1f,
    const float* __restrict__ b1, const float* __restrict__ W2,
    const float* __restrict__ b2, float* __restrict__ out) {
  const int b  = blockIdx.x >> 1;
  const int nh = blockIdx.x & 1;
  const int t  = threadIdx.x;
  const int w  = t >> 6;
  const int l  = t & 63;

  __shared__ ushort sA[40 * 512];   // 40 KB fragment-ordered h_in[b]
  __shared__ float  sS[256];        // this half of s[b,:]
  __shared__ float  sRed[4][128];

  const uint4* g4 = reinterpret_cast<const uint4*>(hinf) + (size_t)b * 2560;
  uint4* s4 = reinterpret_cast<uint4*>(sA);
  for (int u = t; u < 2560; u += 512) s4[u] = g4[u];

  const int n0 = nh * 256 + w * 32;
  const short8* w8 = reinterpret_cast<const short8*>(w1f);
  short8 bfrag[2][5];
#pragma unroll
  for (int nt = 0; nt < 2; ++nt) {
    const int ntg = (n0 >> 4) + nt;
#pragma unroll
    for (int ks = 0; ks < 5; ++ks)
      bfrag[nt][ks] = w8[(ntg * 5 + ks) * 64 + l];
  }
  float bias[2];
#pragma unroll
  for (int nt = 0; nt < 2; ++nt) bias[nt] = b1[n0 + nt * 16 + (l & 15)];

  __syncthreads();

  const short8* a8 = reinterpret_cast<const short8*>(sA);
  float cs[2] = {0.f, 0.f};
  for (int m = 0; m < 8; ++m) {
    short8 af[5];
#pragma unroll
    for (int ks = 0; ks < 5; ++ks) af[ks] = a8[(m * 5 + ks) * 64 + l];
#pragma unroll
    for (int nt = 0; nt < 2; ++nt) {
      f32x4 acc = {0.f, 0.f, 0.f, 0.f};
#pragma unroll
      for (int ks = 0; ks < 5; ++ks)
        acc = __builtin_amdgcn_mfma_f32_16x16x32_bf16(af[ks], bfrag[nt][ks],
                                                      acc, 0, 0, 0);
      float p = 0.f;
#pragma unroll
      for (int r = 0; r < 4; ++r) p += fmaxf(acc[r] + bias[nt], 0.f);
      cs[nt] += p;
    }
  }

#pragma unroll
  for (int nt = 0; nt < 2; ++nt) {
    float v = cs[nt];
    v += __shfl_xor(v, 16);
    v += __shfl_xor(v, 32);
    if ((l >> 4) == 0) sS[w * 32 + nt * 16 + (l & 15)] = v;
  }
  __syncthreads();

  // epilogue: out[b,o] += sum_k sS[k] * W2[nh*256+k][o]  (+ N*b2 once)
  const int o = t & 127, kq = t >> 7;
  const float* W2p = W2 + (size_t)(nh * 256 + kq * 64) * OUT_ + o;
  float acc = 0.f;
#pragma unroll 8
  for (int k = 0; k < 64; ++k) acc += sS[kq * 64 + k] * W2p[(size_t)k * OUT_];
  sRed[kq][o] = acc;
  __syncthreads();
  if (kq == 0) {
    float v = (sRed[0][o] + sRed[1][o]) + (sRed[2][o] + sRed[3][o]);
    if (nh == 0) v += (float)N_ * b2[o];
    atomicAdd(&out[b * OUT_ + o], v);
  }
}

// ---------------------------------------------------------------------------
extern "C" void kernel_launch(void* const* d_in, const int* in_sizes, int n_in,
                              void* d_out, int out_size, void* d_ws, size_t ws_size,
                              hipStream_t stream) {
  const float* atom = (const float*)d_in[0];
  const float* bond = (const float*)d_in[1];
  const float* adj  = (const float*)d_in[2];
  const float* W1   = (const float*)d_in[3];
  const float* b1   = (const float*)d_in[4];
  const float* W2   = (const float*)d_in[5];
  const float* b2   = (const float*)d_in[6];
  float* out = (float*)d_out;

  ushort* hinf = (ushort*)d_ws;                       // 128*2560*16B = 5.24 MB
  ushort* w1f  = hinf + (size_t)B_ * 2560 * 8;        // 160 KB

  hipMemsetAsync(out, 0, (size_t)out_size * sizeof(float), stream);
  k_prep_agg<<<40 + B_ * 8, 256, 0, stream>>>(atom, bond, adj, W1, w1f, hinf);
  k_gemm_out<<<B_ * 2, 512, 0, stream>>>(hinf, w1f, b1, W2, b2, out);
}

// Round 7
// 25.702 us; speedup vs baseline: 3.9448x; 1.2110x over previous
//
#include <hip/hip_runtime.h>
#include <hip/hip_bf16.h>

#define B_   128
#define N_   128
#define FA   64
#define FB   16
#define K1   144   // 2*FA + FB
#define KP   160   // K padded to 5 * 32
#define HID  512
#define OUT_ 128

typedef __attribute__((ext_vector_type(8))) short short8;
typedef __attribute__((ext_vector_type(4))) float f32x4;

__device__ __forceinline__ ushort f2b(float v) {
  __hip_bfloat16 h = __float2bfloat16(v);
  return *reinterpret_cast<ushort*>(&h);
}
__device__ __forceinline__ float4 add4(float4 a, float4 b) {
  return make_float4(a.x + b.x, a.y + b.y, a.z + b.z, a.w + b.w);
}

// ---------------------------------------------------------------------------
// Kernel A: blocks 0..39 convert W1 -> bf16 fragment order; block 40 zeroes
// out; blocks 41.. sparse aggregation + h_in fragment-order build.
// ---------------------------------------------------------------------------
__global__ __launch_bounds__(256) void k_prep_agg(
    const float* __restrict__ atom, const float* __restrict__ bond,
    const float* __restrict__ adj, const float* __restrict__ W1,
    ushort* __restrict__ w1f, ushort* __restrict__ hinf,
    float* __restrict__ out) {
  const int t = threadIdx.x;

  if (blockIdx.x < 40) {                       // ---- W1 conversion role ----
    const int U  = blockIdx.x * 256 + t;
    const int c  = U & 15;
    const int g  = (U >> 4) & 3;
    const int t5 = U >> 6;
    const int ks = t5 % 5;
    const int ntg = t5 / 5;
    const int n  = ntg * 16 + c;
    const int k0 = ks * 32 + g * 8;
    short8 v;
#pragma unroll
    for (int e = 0; e < 8; ++e) {
      const int k = k0 + e;
      v[e] = (short)f2b((k < K1) ? W1[k * HID + n] : 0.f);
    }
    reinterpret_cast<short8*>(w1f)[U] = v;
    return;
  }
  if (blockIdx.x == 40) {                      // ---- zero out[] role ----
    float4* o4 = reinterpret_cast<float4*>(out);
    for (int u = t; u < B_ * OUT_ / 4; u += 256)
      o4[u] = make_float4(0.f, 0.f, 0.f, 0.f);
    return;
  }

  // ---- aggregation role ----
  const int bid = blockIdx.x - 41;
  const int b  = bid >> 3;
  const int m  = bid & 7;
  const int j0 = m * 16;
  const int jl = t >> 4;   // 0..15 local row

  __shared__ float  sAdj[N_][16];    // 8 KB
  __shared__ ushort sList[16][N_];   // 4 KB compact active-i lists (sorted)
  __shared__ int    sCnt[16];
  __shared__ float4 sPart[16][4][4]; // 4 KB is-partials
  __shared__ ushort sRow[16][KP];    // 5 KB

  // stage adj column-slab [128 i][16 j], float4-vectorized
  const float* adjb = adj + (size_t)b * N_ * N_ + j0;
  for (int u = t; u < N_ * 4; u += 256) {
    const int i = u >> 2, q = u & 3;
    *reinterpret_cast<float4*>(&sAdj[i][q * 4]) =
        *reinterpret_cast<const float4*>(&adjb[(size_t)i * N_ + q * 4]);
  }
  __syncthreads();

  // ballot-compact: wave w handles j = w*4 .. w*4+3
  const int wv = t >> 6, l = t & 63;
#pragma unroll
  for (int q = 0; q < 4; ++q) {
    const int jj = wv * 4 + q;
    const float a0 = sAdj[l][jj];
    const float a1 = sAdj[l + 64][jj];
    const unsigned long long m0 = __ballot(a0 != 0.f);
    const unsigned long long m1 = __ballot(a1 != 0.f);
    const int c0 = __popcll(m0);
    unsigned int p0 = __builtin_amdgcn_mbcnt_lo((unsigned)m0, 0u);
    p0 = __builtin_amdgcn_mbcnt_hi((unsigned)(m0 >> 32), p0);
    if (a0 != 0.f) sList[jj][p0] = (ushort)l;
    unsigned int p1 = __builtin_amdgcn_mbcnt_lo((unsigned)m1, 0u);
    p1 = __builtin_amdgcn_mbcnt_hi((unsigned)(m1 >> 32), p1);
    if (a1 != 0.f) sList[jj][c0 + p1] = (ushort)(l + 64);
    if (l == 0) sCnt[jj] = c0 + __popcll(m1);
  }
  __syncthreads();

  // high-MLP gather: thread (jl, fq, is); is-threads stride 4 through the
  // sorted list with float4 loads (64B per (i,j) row covered by 4 fq lanes).
  {
    const int fq = (t >> 2) & 3;
    const int is = t & 3;
    const int cnt = sCnt[jl];
    const float4* bp4 = reinterpret_cast<const float4*>(
        bond + ((size_t)b * N_ * N_ + (j0 + jl)) * FB) + fq;
    // i stride in float4 units: N_*FB/4 = 512
    float4 a0 = {0,0,0,0}, a1 = {0,0,0,0}, a2 = {0,0,0,0}, a3 = {0,0,0,0};
    int e = is;
    for (; e + 12 < cnt; e += 16) {
      const int i0 = sList[jl][e];
      const int i1 = sList[jl][e + 4];
      const int i2 = sList[jl][e + 8];
      const int i3 = sList[jl][e + 12];
      a0 = add4(a0, bp4[(size_t)i0 * 512]);
      a1 = add4(a1, bp4[(size_t)i1 * 512]);
      a2 = add4(a2, bp4[(size_t)i2 * 512]);
      a3 = add4(a3, bp4[(size_t)i3 * 512]);
    }
    for (; e < cnt; e += 4) a0 = add4(a0, bp4[(size_t)sList[jl][e] * 512]);
    sPart[jl][fq][is] = add4(add4(a0, a1), add4(a2, a3));
  }
  __syncthreads();

  // combine is-partials + build bf16 row [atom | atom*deg | agg | 0-pad]
  {
    const int f = t & 15;
    const float* pc = reinterpret_cast<const float*>(&sPart[jl][f >> 2][0]);
    const float aggv = ((pc[f & 3] + pc[4 + (f & 3)]) +
                        (pc[8 + (f & 3)] + pc[12 + (f & 3)]));
    const float deg = (float)sCnt[jl];
    const float* ab = atom + ((size_t)b * N_ + j0 + jl) * FA;
    for (int c = f; c < FA; c += 16) {
      const float av = ab[c];
      sRow[jl][c]      = f2b(av);
      sRow[jl][FA + c] = f2b(av * deg);
    }
    sRow[jl][2 * FA + f] = f2b(aggv);
    sRow[jl][K1 + f]     = 0;
  }
  __syncthreads();

  uint4* dst = reinterpret_cast<uint4*>(hinf) + (size_t)(b * 8 + m) * 320;
  for (int u = t; u < 320; u += 256) {
    const int s = u >> 4, j2 = u & 15;        // s = ks*4 + g
    const int ks = s >> 2, g = s & 3;
    dst[ks * 64 + g * 16 + j2] =
        *reinterpret_cast<const uint4*>(&sRow[j2][s * 8]);
  }
}

// ---------------------------------------------------------------------------
// Fused GEMM1 + bias + relu + column-sum + (s @ W2) epilogue.
// block = (b, n-half). 512 thr = 8 waves; wave w owns 32 cols of the half.
// out must be zero on entry (kernel A block 40); exactly 2 commutative fp32
// atomicAdds per element -> deterministic.
// ---------------------------------------------------------------------------
__global__ __launch_bounds__(512) void k_gemm_out(
    const ushort* __restrict__ hinf, const ushort* __restrict__ w1f,
    const float* __restrict__ b1, const float* __restrict__ W2,
    const float* __restrict__ b2, float* __restrict__ out) {
  const int b  = blockIdx.x >> 1;
  const int nh = blockIdx.x & 1;
  const int t  = threadIdx.x;
  const int w  = t >> 6;
  const int l  = t & 63;

  __shared__ ushort sA[40 * 512];   // 40 KB fragment-ordered h_in[b]
  __shared__ float  sS[256];        // this half of s[b,:]
  __shared__ float  sRed[4][128];

  const uint4* g4 = reinterpret_cast<const uint4*>(hinf) + (size_t)b * 2560;
  uint4* s4 = reinterpret_cast<uint4*>(sA);
  for (int u = t; u < 2560; u += 512) s4[u] = g4[u];

  const int n0 = nh * 256 + w * 32;
  const short8* w8 = reinterpret_cast<const short8*>(w1f);
  short8 bfrag[2][5];
#pragma unroll
  for (int nt = 0; nt < 2; ++nt) {
    const int ntg = (n0 >> 4) + nt;
#pragma unroll
    for (int ks = 0; ks < 5; ++ks)
      bfrag[nt][ks] = w8[(ntg * 5 + ks) * 64 + l];
  }
  float bias[2];
#pragma unroll
  for (int nt = 0; nt < 2; ++nt) bias[nt] = b1[n0 + nt * 16 + (l & 15)];

  __syncthreads();

  const short8* a8 = reinterpret_cast<const short8*>(sA);
  float cs[2] = {0.f, 0.f};
  for (int m = 0; m < 8; ++m) {
    short8 af[5];
#pragma unroll
    for (int ks = 0; ks < 5; ++ks) af[ks] = a8[(m * 5 + ks) * 64 + l];
#pragma unroll
    for (int nt = 0; nt < 2; ++nt) {
      f32x4 acc = {0.f, 0.f, 0.f, 0.f};
#pragma unroll
      for (int ks = 0; ks < 5; ++ks)
        acc = __builtin_amdgcn_mfma_f32_16x16x32_bf16(af[ks], bfrag[nt][ks],
                                                      acc, 0, 0, 0);
      float p = 0.f;
#pragma unroll
      for (int r = 0; r < 4; ++r) p += fmaxf(acc[r] + bias[nt], 0.f);
      cs[nt] += p;
    }
  }

#pragma unroll
  for (int nt = 0; nt < 2; ++nt) {
    float v = cs[nt];
    v += __shfl_xor(v, 16);
    v += __shfl_xor(v, 32);
    if ((l >> 4) == 0) sS[w * 32 + nt * 16 + (l & 15)] = v;
  }
  __syncthreads();

  // epilogue: out[b,o] += sum_k sS[k] * W2[nh*256+k][o]  (+ N*b2 once)
  const int o = t & 127, kq = t >> 7;
  const float* W2p = W2 + (size_t)(nh * 256 + kq * 64) * OUT_ + o;
  float acc = 0.f;
#pragma unroll 8
  for (int k = 0; k < 64; ++k) acc += sS[kq * 64 + k] * W2p[(size_t)k * OUT_];
  sRed[kq][o] = acc;
  __syncthreads();
  if (kq == 0) {
    float v = (sRed[0][o] + sRed[1][o]) + (sRed[2][o] + sRed[3][o]);
    if (nh == 0) v += (float)N_ * b2[o];
    atomicAdd(&out[b * OUT_ + o], v);
  }
}

// ---------------------------------------------------------------------------
extern "C" void kernel_launch(void* const* d_in, const int* in_sizes, int n_in,
                              void* d_out, int out_size, void* d_ws, size_t ws_size,
                              hipStream_t stream) {
  const float* atom = (const float*)d_in[0];
  const float* bond = (const float*)d_in[1];
  const float* adj  = (const float*)d_in[2];
  const float* W1   = (const float*)d_in[3];
  const float* b1   = (const float*)d_in[4];
  const float* W2   = (const float*)d_in[5];
  const float* b2   = (const float*)d_in[6];
  float* out = (float*)d_out;

  ushort* hinf = (ushort*)d_ws;                       // 128*2560*16B = 5.24 MB
  ushort* w1f  = hinf + (size_t)B_ * 2560 * 8;        // 160 KB

  k_prep_agg<<<41 + B_ * 8, 256, 0, stream>>>(atom, bond, adj, W1, w1f, hinf,
                                              out);
  k_gemm_out<<<B_ * 2, 512, 0, stream>>>(hinf, w1f, b1, W2, b2, out);
}